// Round 18
// baseline (1248.685 us; speedup 1.0000x reference)
//
#include <hip/hip_runtime.h>

// RecurrentSNN: B=256, T=1024, F=64, H=512, O=64
// out = concat(mem_rec [B,T,O], spk_rec [B,T,O]) f32.
//
// Round-18: fuse A+B -> snn_ab. Block=b, thread=h: layer-1 state lives in
// registers across the whole chunk, cur1 is never materialized (r11 paid
// 128MB write + 128MB read + a stall-bound scalar-broadcast GEMV for it).
// x rows arrive via r5's PROVEN wave-uniform float4 VMEM pattern (no
// traffic inflation: r5 FETCH=66MB), ping-pong 2-bank prefetch (row t+2
// in flight under step t+1's fma wall; no barriers anywhere).
// Spikes written f32, [row][h] coalesced -- exactly what r11-C reads.
//  C: r11 verbatim (113us/chunk proven). D: verbatim. Host: nch {4,8,16}.
// All fma chains verbatim (FMA4 == AQ order) -> absmax exactly 0.04394531.

namespace {
constexpr int kB = 256;
constexpr int kT = 1024;
constexpr int kF = 64;
constexpr int kH = 512;
constexpr int kO = 64;
constexpr float kBeta = 0.9f;
constexpr float kThresh = 1.0f;
}  // namespace

typedef __attribute__((ext_vector_type(16))) float f32x16;

#define PIN8(p)                                                            \
  asm volatile("" : "+v"((p)[0]), "+v"((p)[1]), "+v"((p)[2]),              \
                    "+v"((p)[3]), "+v"((p)[4]), "+v"((p)[5]),              \
                    "+v"((p)[6]), "+v"((p)[7]))

#define BARRIER() asm volatile("s_waitcnt lgkmcnt(0)\n\ts_barrier" ::: "memory")

// 64 floats -> 4 SGPR x16 banks, loads + drain in ONE asm (zero window).
#define SLOAD64(sx0, sx1, sx2, sx3, ptr)                                   \
  asm volatile("s_load_dwordx16 %0, %4, 0x0\n\t"                           \
               "s_load_dwordx16 %1, %4, 0x40\n\t"                          \
               "s_load_dwordx16 %2, %4, 0x80\n\t"                          \
               "s_load_dwordx16 %3, %4, 0xc0\n\t"                          \
               "s_waitcnt lgkmcnt(0)"                                      \
               : "=&s"(sx0), "=&s"(sx1), "=&s"(sx2), "=&s"(sx3)            \
               : "s"(ptr) : "memory")

// ======================= AB: layer-1 GEMV + scan, fused ===================
// FMA4 chain identical to r11-A's AQ (c0..c3, q ascending) -> bit-exact.
#define FMA4(v, q)                                                         \
  c0 = fmaf((v).x, w[4 * (q) + 0], c0);                                    \
  c1 = fmaf((v).y, w[4 * (q) + 1], c1);                                    \
  c2 = fmaf((v).z, w[4 * (q) + 2], c2);                                    \
  c3 = fmaf((v).w, w[4 * (q) + 3], c3);

#define LDB(bk, tt)                                                        \
  do {                                                                     \
    const float4* p = xv + (size_t)(tt) * 16;                              \
    bk##0 = p[0]; bk##1 = p[1]; bk##2 = p[2]; bk##3 = p[3];                \
    bk##4 = p[4]; bk##5 = p[5]; bk##6 = p[6]; bk##7 = p[7];                \
    bk##8 = p[8]; bk##9 = p[9]; bk##10 = p[10]; bk##11 = p[11];            \
    bk##12 = p[12]; bk##13 = p[13]; bk##14 = p[14]; bk##15 = p[15];        \
  } while (0)

#define STEP(bk, tt)                                                       \
  do {                                                                     \
    float c0 = bias, c1 = 0.0f, c2 = 0.0f, c3 = 0.0f;                      \
    FMA4(bk##0, 0) FMA4(bk##1, 1) FMA4(bk##2, 2) FMA4(bk##3, 3)            \
    FMA4(bk##4, 4) FMA4(bk##5, 5) FMA4(bk##6, 6) FMA4(bk##7, 7)            \
    FMA4(bk##8, 8) FMA4(bk##9, 9) FMA4(bk##10, 10) FMA4(bk##11, 11)        \
    FMA4(bk##12, 12) FMA4(bk##13, 13) FMA4(bk##14, 14) FMA4(bk##15, 15)    \
    const float cur = (c0 + c1) + (c2 + c3);                               \
    mem1 = kBeta * mem1 + cur - rst1;                                      \
    rst1 = (mem1 > kThresh) ? 1.0f : 0.0f;                                 \
    sp[(size_t)(tt) * kH] = rst1;                                          \
  } while (0)

__global__ __launch_bounds__(512)
void snn_ab(const float* __restrict__ x, const float* __restrict__ W_in,
            const float* __restrict__ b_in, float* __restrict__ spk,
            float* __restrict__ state, int t0, int ntc) {
  const int b = blockIdx.x;
  const int j = threadIdx.x;  // h

  // W_in row h resident (per-lane gather, once)
  float w[64];
  {
    const float4* wiv = reinterpret_cast<const float4*>(W_in) + j * 16;
#pragma unroll
    for (int q = 0; q < 16; ++q) {
      const float4 v = wiv[q];
      w[4*q+0] = v.x; w[4*q+1] = v.y; w[4*q+2] = v.z; w[4*q+3] = v.w;
    }
  }
  float bias = b_in[j];
  PIN8(w + 0);  PIN8(w + 8);  PIN8(w + 16); PIN8(w + 24);
  PIN8(w + 32); PIN8(w + 40); PIN8(w + 48); PIN8(w + 56);
  asm volatile("" : "+v"(bias));

  float* m1s = state;
  float* r1s = state + kB * kH;
  const int idx = b * kH + j;
  float mem1 = 0.0f, rst1 = 0.0f;
  if (t0 != 0) { mem1 = m1s[idx]; rst1 = r1s[idx]; }

  const float4* xv =
      reinterpret_cast<const float4*>(x + ((size_t)b * kT + t0) * kF);
  float* sp = spk + (size_t)b * ntc * kH + j;

  // ping-pong banks: row t+1 (and t+2) in flight under the current fma wall
  float4 a0, a1, a2, a3, a4, a5, a6, a7, a8, a9, a10, a11, a12, a13, a14, a15;
  float4 e0, e1, e2, e3, e4, e5, e6, e7, e8, e9, e10, e11, e12, e13, e14, e15;

  LDB(a, 0);
#pragma unroll 1
  for (int t = 0; t < ntc; t += 2) {
    LDB(e, t + 1);                        // odd row in flight under even fma
    STEP(a, t);
    LDB(a, (t + 2 < ntc) ? t + 2 : t);    // next even row under odd fma
    STEP(e, t + 1);
  }

  m1s[idx] = mem1;
  r1s[idx] = rst1;
}

// ======================= C: spikes @ W_out^T + b_out (r11) ================
#define SC(i) ((i) < 16 ? m0[(i)] : (i) < 32 ? m1[(i)-16]                  \
             : (i) < 48 ? m2[(i)-32] : m3[(i)-48])

#define CROW(rr)                                                           \
  do {                                                                     \
    const float* sp_ = spkrow + (size_t)(rr) * kH;                         \
    f32x16 m0, m1, m2, m3;                                                 \
    SLOAD64(m0, m1, m2, m3, sp_);                                          \
    float a0 = 0.0f, a1 = 0.0f, a2 = 0.0f, a3 = 0.0f;                      \
    _Pragma("unroll") for (int q = 0; q < 16; ++q) {                       \
      a0 = fmaf(SC(4 * q + 0), wout[4 * q + 0], a0);                       \
      a1 = fmaf(SC(4 * q + 1), wout[4 * q + 1], a1);                       \
      a2 = fmaf(SC(4 * q + 2), wout[4 * q + 2], a2);                       \
      a3 = fmaf(SC(4 * q + 3), wout[4 * q + 3], a3);                       \
    }                                                                      \
    red[buf][rr][s][o] = (a0 + a1) + (a2 + a3);                            \
  } while (0)

__global__ __launch_bounds__(512)
void snn_coutC(const float* __restrict__ spk, const float* __restrict__ W_out,
               const float* __restrict__ b_out, float* __restrict__ cout,
               int ntc) {
  const int j = threadIdx.x;
  const int o = j & 63;
  const int s = j >> 6;
  const int s_u = __builtin_amdgcn_readfirstlane(s);  // SGPR-addressable
  const size_t row0 = (size_t)blockIdx.x * 64;

  __shared__ float red[2][8][8][64];  // [buf][rowInBatch][slice][o]

  float wout[64];
  {
    const float4* wov =
        reinterpret_cast<const float4*>(W_out) + o * (kH / 4) + s * 16;
#pragma unroll
    for (int q = 0; q < 16; ++q) {
      const float4 v = wov[q];
      wout[4*q+0] = v.x; wout[4*q+1] = v.y;
      wout[4*q+2] = v.z; wout[4*q+3] = v.w;
    }
  }
  float bout = b_out[o];
  PIN8(wout + 0);  PIN8(wout + 8);  PIN8(wout + 16); PIN8(wout + 24);
  PIN8(wout + 32); PIN8(wout + 40); PIN8(wout + 48); PIN8(wout + 56);
  asm volatile("" : "+v"(bout));

#pragma unroll 1
  for (int rb = 0; rb < 64; rb += 8) {
    const int buf = (rb >> 3) & 1;
    const float* spkrow = spk + (row0 + (size_t)rb) * kH + s_u * 64;

    CROW(0); CROW(1); CROW(2); CROW(3);
    CROW(4); CROW(5); CROW(6); CROW(7);

    BARRIER();  // red visible; single barrier per batch (dbuf separation)

    float co = bout;
    co += red[buf][s][0][o]; co += red[buf][s][1][o];
    co += red[buf][s][2][o]; co += red[buf][s][3][o];
    co += red[buf][s][4][o]; co += red[buf][s][5][o];
    co += red[buf][s][6][o]; co += red[buf][s][7][o];
    cout[(row0 + (size_t)(rb + s)) * kO + o] = co;
  }
}

// ======================= D: layer-2 scan (per b,o) ========================
#define DSTEP(gk, tt)                                                      \
  do {                                                                     \
    memo = kBeta * memo + (gk) - rsto;                                     \
    const float so = (memo > kThresh) ? 1.0f : 0.0f;                       \
    rsto = so;                                                             \
    om[(size_t)(tt) * kO] = memo;                                          \
    os[(size_t)(tt) * kO] = so;                                            \
    const int tn_ = ((tt) + 8 < ntc) ? (tt) + 8 : ntc - 1;                 \
    gk = dp[(size_t)tn_ * kO];                                             \
  } while (0)

__global__ __launch_bounds__(64)
void snn_memoD(const float* __restrict__ cout, float* __restrict__ out,
               float* __restrict__ state, int t0, int ntc) {
  const int b = blockIdx.x;
  const int o = threadIdx.x;
  float* mos = state + 2 * kB * kH;
  float* ros = mos + kB * kO;
  const int idx = b * kO + o;
  float memo = 0.0f, rsto = 0.0f;
  if (t0 != 0) { memo = mos[idx]; rsto = ros[idx]; }

  const float* dp = cout + (size_t)b * ntc * kO + o;
  float* om = out + ((size_t)b * kT + t0) * kO + o;
  float* os = om + (size_t)kB * kT * kO;

  float g0 = dp[0 * (size_t)kO], g1 = dp[1 * (size_t)kO];
  float g2 = dp[2 * (size_t)kO], g3 = dp[3 * (size_t)kO];
  float g4 = dp[4 * (size_t)kO], g5 = dp[5 * (size_t)kO];
  float g6 = dp[6 * (size_t)kO], g7 = dp[7 * (size_t)kO];

#pragma unroll 1
  for (int t = 0; t < ntc; t += 8) {
    DSTEP(g0, t + 0); DSTEP(g1, t + 1); DSTEP(g2, t + 2); DSTEP(g3, t + 3);
    DSTEP(g4, t + 4); DSTEP(g5, t + 5); DSTEP(g6, t + 6); DSTEP(g7, t + 7);
  }
  mos[idx] = memo;
  ros[idx] = rsto;
}

// ======================= fallback (round-5, proven 1101us) ================
__global__ __launch_bounds__(256)
void warm_x_kernel(const float4* __restrict__ p, int n4) {
  float acc = 0.0f;
  for (int i = blockIdx.x * blockDim.x + threadIdx.x; i < n4;
       i += gridDim.x * blockDim.x) {
    const float4 v = p[i];
    acc += v.x + v.y + v.z + v.w;
  }
  asm volatile("" ::"v"(acc));
}

__global__ __launch_bounds__(512)
__attribute__((amdgpu_waves_per_eu(2, 2)))
void snn_fused5(const float* __restrict__ x, const float* __restrict__ W_in,
                const float* __restrict__ b_in,
                const float* __restrict__ W_out,
                const float* __restrict__ b_out, float* __restrict__ out) {
  const int b = blockIdx.x;
  const int j = threadIdx.x;
  const int o = j & 63;
  const int s = j >> 6;
  __shared__ float red[2][8][64];
  float win[kF];
  {
    const float4* wiv = reinterpret_cast<const float4*>(W_in) + j * 16;
#pragma unroll
    for (int q = 0; q < 16; ++q) {
      const float4 v = wiv[q];
      win[4 * q] = v.x; win[4 * q + 1] = v.y;
      win[4 * q + 2] = v.z; win[4 * q + 3] = v.w;
    }
  }
  float wout[64];
  {
    const float4* wov =
        reinterpret_cast<const float4*>(W_out) + o * 128 + s * 16;
#pragma unroll
    for (int q = 0; q < 16; ++q) {
      const float4 v = wov[q];
      wout[4 * q] = v.x; wout[4 * q + 1] = v.y;
      wout[4 * q + 2] = v.z; wout[4 * q + 3] = v.w;
    }
  }
  float bin_j = b_in[j];
  float bout_o = b_out[o];
  PIN8(win + 0);  PIN8(win + 8);  PIN8(win + 16); PIN8(win + 24);
  PIN8(win + 32); PIN8(win + 40); PIN8(win + 48); PIN8(win + 56);
  PIN8(wout + 0);  PIN8(wout + 8);  PIN8(wout + 16); PIN8(wout + 24);
  PIN8(wout + 32); PIN8(wout + 40); PIN8(wout + 48); PIN8(wout + 56);
  asm volatile("" : "+v"(bin_j), "+v"(bout_o));
  float mem1 = 0.0f, rst1 = 0.0f, memo = 0.0f, rsto = 0.0f;
  unsigned long long mask = 0ull;
  const float4* xv = reinterpret_cast<const float4*>(x + (size_t)b * kT * kF);
  float* out_mem = out + (size_t)b * kT * kO + o;
  float* out_spk = out_mem + (size_t)kB * kT * kO;
  float4 x0, x1, x2, x3, x4, x5, x6, x7, x8, x9, x10, x11, x12, x13, x14, x15;
#define LOADX(tt)                                                          \
  do {                                                                     \
    const float4* xp = xv + (size_t)(tt) * 16;                             \
    x0 = xp[0]; x1 = xp[1]; x2 = xp[2]; x3 = xp[3];                        \
    x4 = xp[4]; x5 = xp[5]; x6 = xp[6]; x7 = xp[7];                        \
    x8 = xp[8]; x9 = xp[9]; x10 = xp[10]; x11 = xp[11];                    \
    x12 = xp[12]; x13 = xp[13]; x14 = xp[14]; x15 = xp[15];                \
  } while (0)
#define L1Q(q)                                                             \
  c0 = fmaf(x##q.x, win[4 * q + 0], c0);                                   \
  c1 = fmaf(x##q.y, win[4 * q + 1], c1);                                   \
  c2 = fmaf(x##q.z, win[4 * q + 2], c2);                                   \
  c3 = fmaf(x##q.w, win[4 * q + 3], c3);
#define LAYER1F()                                                          \
  do {                                                                     \
    float c0 = bin_j, c1 = 0.0f, c2 = 0.0f, c3 = 0.0f;                     \
    L1Q(0) L1Q(1) L1Q(2) L1Q(3) L1Q(4) L1Q(5) L1Q(6) L1Q(7)                \
    L1Q(8) L1Q(9) L1Q(10) L1Q(11) L1Q(12) L1Q(13) L1Q(14) L1Q(15)          \
    const float cur1v = (c0 + c1) + (c2 + c3);                             \
    mem1 = kBeta * mem1 + cur1v - rst1;                                    \
    const bool p = mem1 > kThresh;                                         \
    mask = __ballot(p);                                                    \
    rst1 = p ? 1.0f : 0.0f;                                                \
  } while (0)
#define L2QS(q)                                                            \
  {                                                                        \
    const float f0 = ((mlo >> (4 * (q) + 0)) & 1u) ? 1.0f : 0.0f;          \
    const float f1 = ((mlo >> (4 * (q) + 1)) & 1u) ? 1.0f : 0.0f;          \
    const float f2 = ((mlo >> (4 * (q) + 2)) & 1u) ? 1.0f : 0.0f;          \
    const float f3 = ((mlo >> (4 * (q) + 3)) & 1u) ? 1.0f : 0.0f;          \
    a0 = fmaf(f0, wout[4 * (q) + 0], a0);                                  \
    a1 = fmaf(f1, wout[4 * (q) + 1], a1);                                  \
    a2 = fmaf(f2, wout[4 * (q) + 2], a2);                                  \
    a3 = fmaf(f3, wout[4 * (q) + 3], a3);                                  \
  }
#define L2E(acc, q, i)                                                     \
  acc = acc + __uint_as_float(                                             \
      (unsigned)__builtin_amdgcn_sbfe((int)vmhi, 4 * (q) + (i)-32, 1) &    \
      __float_as_uint(wout[4 * (q) + (i)]));
#define L2QV(q)                                                            \
  { L2E(a0, q, 0) L2E(a1, q, 1) L2E(a2, q, 2) L2E(a3, q, 3) }
#define LAYER2F(buf)                                                       \
  do {                                                                     \
    const unsigned mlo = (unsigned)mask;                                   \
    unsigned vmhi = (unsigned)(mask >> 32);                                \
    asm volatile("" : "+v"(vmhi));                                         \
    float a0 = 0.0f, a1 = 0.0f, a2 = 0.0f, a3 = 0.0f;                      \
    L2QS(0) L2QS(1) L2QS(2) L2QS(3) L2QS(4) L2QS(5) L2QS(6) L2QS(7)        \
    L2QV(8) L2QV(9) L2QV(10) L2QV(11) L2QV(12) L2QV(13) L2QV(14) L2QV(15)  \
    red[(buf)][s][o] = (a0 + a1) + (a2 + a3);                              \
  } while (0)
  LOADX(0);
  LAYER1F();
  LOADX(1);
  for (int t = 1; t < kT; ++t) {
    LAYER2F((t - 1) & 1);
    BARRIER();
    float r0, r1, r2, r3, r4, r5, r6, r7;
    const int buf = (t - 1) & 1;
    if (s == 0) {
      r0 = red[buf][0][o]; r1 = red[buf][1][o];
      r2 = red[buf][2][o]; r3 = red[buf][3][o];
      r4 = red[buf][4][o]; r5 = red[buf][5][o];
      r6 = red[buf][6][o]; r7 = red[buf][7][o];
    }
    LAYER1F();
    const int tn = (t + 1 < kT) ? (t + 1) : (kT - 1);
    LOADX(tn);
    if (s == 0) {
      float co = bout_o;
      co += r0; co += r1; co += r2; co += r3;
      co += r4; co += r5; co += r6; co += r7;
      memo = kBeta * memo + co - rsto;
      const float so = (memo > kThresh) ? 1.0f : 0.0f;
      rsto = so;
      out_mem[(t - 1) * kO] = memo;
      out_spk[(t - 1) * kO] = so;
    }
  }
  LAYER2F((kT - 1) & 1);
  BARRIER();
  if (s == 0) {
    const int buf = (kT - 1) & 1;
    float co = bout_o;
    co += red[buf][0][o]; co += red[buf][1][o];
    co += red[buf][2][o]; co += red[buf][3][o];
    co += red[buf][4][o]; co += red[buf][5][o];
    co += red[buf][6][o]; co += red[buf][7][o];
    memo = kBeta * memo + co - rsto;
    const float so = (memo > kThresh) ? 1.0f : 0.0f;
    out_mem[(kT - 1) * kO] = memo;
    out_spk[(kT - 1) * kO] = so;
  }
}

// ======================= host ==============================================
extern "C" void kernel_launch(void* const* d_in, const int* in_sizes, int n_in,
                              void* d_out, int out_size, void* d_ws,
                              size_t ws_size, hipStream_t stream) {
  const float* x = (const float*)d_in[0];
  const float* W_in = (const float*)d_in[1];
  const float* b_in = (const float*)d_in[2];
  const float* W_out = (const float*)d_in[3];
  const float* b_out = (const float*)d_in[4];
  float* out = (float*)d_out;

  const size_t state_bytes = ((size_t)2 * kB * kH + 2 * kB * kO) * 4;
  int nch = 0;
  for (int c : {4, 8, 16}) {   // nch=2 would spill the spike buffer past L3
    const int ntc_c = kT / c;
    const size_t need = (size_t)kB * ntc_c * (kH + kO) * 4 + state_bytes;
    if (need <= ws_size) { nch = c; break; }
  }

  if (nch) {
    const int ntc = kT / nch;
    float* spkb = (float*)d_ws;
    float* coutb = spkb + (size_t)kB * ntc * kH;
    float* state = coutb + (size_t)kB * ntc * kO;

    const int rows = kB * ntc;
    const int gC = rows / 64;

    for (int c = 0; c < nch; ++c) {
      const int t0 = c * ntc;
      hipLaunchKernelGGL(snn_ab, dim3(kB), dim3(512), 0, stream,
                         x, W_in, b_in, spkb, state, t0, ntc);
      hipLaunchKernelGGL(snn_coutC, dim3(gC), dim3(512), 0, stream,
                         spkb, W_out, b_out, coutb, ntc);
      hipLaunchKernelGGL(snn_memoD, dim3(kB), dim3(64), 0, stream,
                         coutb, out, state, t0, ntc);
    }
  } else {
    const int n4 = kB * kT * kF / 4;
    hipLaunchKernelGGL(warm_x_kernel, dim3(1024), dim3(256), 0, stream,
                       (const float4*)x, n4);
    hipLaunchKernelGGL(snn_fused5, dim3(kB), dim3(512), 0, stream,
                       x, W_in, b_in, W_out, b_out, out);
  }
}

// Round 19
// 1023.270 us; speedup vs baseline: 1.2203x; 1.2203x over previous
//
#include <hip/hip_runtime.h>

// RecurrentSNN: B=256, T=1024, F=64, H=512, O=64
// out = concat(mem_rec [B,T,O], spk_rec [B,T,O]) f32.
//
// Round-19: restore round-11 verbatim — the best-measured configuration
// (1027.7 us). Rounds 12-18 falsified every remaining single-kernel lever:
//  - SGPR software-pipelining: allocator may copy/split pending-load regs
//    in any nonzero issue->wait window (r12/r13 correctness failures).
//  - scalar-load COUNT reduction: A unchanged at iso-occupancy (r15),
//    C regressed to VALU-bound bit-unpack (r17).
//  - occupancy forcing (waves_per_eu): trades TLP for residency at a net
//    loss in every latency-bound kernel (r14/r15).
//  - scan-fused GEMV: scan topology caps TLP at 2 waves/SIMD -> ~2x
//    latency-cover loss vs split-A's 4/SIMD (r16/r18: 207 vs 114).
// Structure: A thread=h scalar-x GEMV | B in-place scan | C scalar-spike
// GEMV | D scan; nch=4 chunks, all intermediates L3-resident.
// All fma chains preserved -> absmax exactly 0.04394531.

namespace {
constexpr int kB = 256;
constexpr int kT = 1024;
constexpr int kF = 64;
constexpr int kH = 512;
constexpr int kO = 64;
constexpr float kBeta = 0.9f;
constexpr float kThresh = 1.0f;
}  // namespace

typedef __attribute__((ext_vector_type(16))) float f32x16;

#define PIN8(p)                                                            \
  asm volatile("" : "+v"((p)[0]), "+v"((p)[1]), "+v"((p)[2]),              \
                    "+v"((p)[3]), "+v"((p)[4]), "+v"((p)[5]),              \
                    "+v"((p)[6]), "+v"((p)[7]))

#define BARRIER() asm volatile("s_waitcnt lgkmcnt(0)\n\ts_barrier" ::: "memory")

// ======================= A: cur1 = x @ W_in^T + b_in ======================
#define SX(i) ((i) < 16 ? sx0[(i)] : (i) < 32 ? sx1[(i)-16]                \
             : (i) < 48 ? sx2[(i)-32] : sx3[(i)-48])
#define AQ(q)                                                              \
  c0 = fmaf(SX(4*(q)+0), w[4*(q)+0], c0);                                  \
  c1 = fmaf(SX(4*(q)+1), w[4*(q)+1], c1);                                  \
  c2 = fmaf(SX(4*(q)+2), w[4*(q)+2], c2);                                  \
  c3 = fmaf(SX(4*(q)+3), w[4*(q)+3], c3);

__global__ __launch_bounds__(512)
void snn_curA(const float* __restrict__ x, const float* __restrict__ W_in,
              const float* __restrict__ b_in, float* __restrict__ cur1,
              int t0, int ntc, int l2ntc, int rpb) {
  const int l = threadIdx.x & 63;
  const int s = threadIdx.x >> 6;
  const int h = s * 64 + l;

  // W_in row h resident (per-lane gather, ONCE per kernel)
  float w[64];
  {
    const float4* wiv = reinterpret_cast<const float4*>(W_in) + h * 16;
#pragma unroll
    for (int q = 0; q < 16; ++q) {
      const float4 v = wiv[q];
      w[4*q+0] = v.x; w[4*q+1] = v.y; w[4*q+2] = v.z; w[4*q+3] = v.w;
    }
  }
  float binh = b_in[h];
  PIN8(w + 0);  PIN8(w + 8);  PIN8(w + 16); PIN8(w + 24);
  PIN8(w + 32); PIN8(w + 40); PIN8(w + 48); PIN8(w + 56);
  asm volatile("" : "+v"(binh));

  const int row0 = blockIdx.x * rpb;
#pragma unroll 1
  for (int r = 0; r < rpb; ++r) {
    const int row = row0 + r;
    const int b = row >> l2ntc;
    const int tc = row & (ntc - 1);
    const float* xp = x + ((size_t)b * kT + (size_t)(t0 + tc)) * kF;
    f32x16 sx0, sx1, sx2, sx3;
    asm volatile("s_load_dwordx16 %0, %4, 0x0\n\t"
                 "s_load_dwordx16 %1, %4, 0x40\n\t"
                 "s_load_dwordx16 %2, %4, 0x80\n\t"
                 "s_load_dwordx16 %3, %4, 0xc0"
                 : "=&s"(sx0), "=&s"(sx1), "=&s"(sx2), "=&s"(sx3)
                 : "s"(xp));
    asm volatile("s_waitcnt lgkmcnt(0)"
                 : "+s"(sx0), "+s"(sx1), "+s"(sx2), "+s"(sx3) :: "memory");
    float c0 = binh, c1 = 0.0f, c2 = 0.0f, c3 = 0.0f;
    AQ(0) AQ(1) AQ(2) AQ(3) AQ(4) AQ(5) AQ(6) AQ(7)
    AQ(8) AQ(9) AQ(10) AQ(11) AQ(12) AQ(13) AQ(14) AQ(15)
    cur1[(size_t)row * kH + h] = (c0 + c1) + (c2 + c3);
  }
}

// ======================= B: layer-1 scan (per b,h) ========================
#define BSTEP(fk, tt)                                                      \
  do {                                                                     \
    mem1 = kBeta * mem1 + (fk) - rst1;                                     \
    const bool pr = mem1 > kThresh;                                        \
    rst1 = pr ? 1.0f : 0.0f;                                               \
    cp[(size_t)(tt) * kH] = rst1;  /* spike overwrites cur1 slot */        \
    const int tn_ = ((tt) + 8 < ntc) ? (tt) + 8 : ntc - 1;                 \
    fk = cp[(size_t)tn_ * kH];     /* prefetch (clamped ones unused) */    \
  } while (0)

__global__ __launch_bounds__(512)
void snn_scanB(float* __restrict__ cs, float* __restrict__ state,
               int t0, int ntc) {
  const int b = blockIdx.x;
  const int h = threadIdx.x;
  float* m1s = state;
  float* r1s = state + kB * kH;
  const int idx = b * kH + h;
  float mem1 = 0.0f, rst1 = 0.0f;
  if (t0 != 0) { mem1 = m1s[idx]; rst1 = r1s[idx]; }

  float* cp = cs + (size_t)b * ntc * kH + h;
  float f0 = cp[0 * (size_t)kH], f1 = cp[1 * (size_t)kH];
  float f2 = cp[2 * (size_t)kH], f3 = cp[3 * (size_t)kH];
  float f4 = cp[4 * (size_t)kH], f5 = cp[5 * (size_t)kH];
  float f6 = cp[6 * (size_t)kH], f7 = cp[7 * (size_t)kH];

#pragma unroll 1
  for (int t = 0; t < ntc; t += 8) {
    BSTEP(f0, t + 0); BSTEP(f1, t + 1); BSTEP(f2, t + 2); BSTEP(f3, t + 3);
    BSTEP(f4, t + 4); BSTEP(f5, t + 5); BSTEP(f6, t + 6); BSTEP(f7, t + 7);
  }
  m1s[idx] = mem1;
  r1s[idx] = rst1;
}

// ======================= C: cur_out = spikes @ W_out^T + b_out ============
// Wave s reads its slice's spikes (256B wave-uniform, SGPR address via
// readfirstlane) with merged s_load+wait; default occupancy provides the
// TLP that hides the zero-window waits (r11: 113us/chunk).
#define SC(i) ((i) < 16 ? m0[(i)] : (i) < 32 ? m1[(i)-16]                  \
             : (i) < 48 ? m2[(i)-32] : m3[(i)-48])

#define CROW(rr)                                                           \
  do {                                                                     \
    const float* sp = spkrow + (size_t)(rr) * kH;                          \
    f32x16 m0, m1, m2, m3;                                                 \
    asm volatile("s_load_dwordx16 %0, %4, 0x0\n\t"                         \
                 "s_load_dwordx16 %1, %4, 0x40\n\t"                        \
                 "s_load_dwordx16 %2, %4, 0x80\n\t"                        \
                 "s_load_dwordx16 %3, %4, 0xc0"                            \
                 : "=&s"(m0), "=&s"(m1), "=&s"(m2), "=&s"(m3)              \
                 : "s"(sp));                                               \
    asm volatile("s_waitcnt lgkmcnt(0)"                                    \
                 : "+s"(m0), "+s"(m1), "+s"(m2), "+s"(m3) :: "memory");    \
    float a0 = 0.0f, a1 = 0.0f, a2 = 0.0f, a3 = 0.0f;                      \
    _Pragma("unroll") for (int q = 0; q < 16; ++q) {                       \
      a0 = fmaf(SC(4 * q + 0), wout[4 * q + 0], a0);                       \
      a1 = fmaf(SC(4 * q + 1), wout[4 * q + 1], a1);                       \
      a2 = fmaf(SC(4 * q + 2), wout[4 * q + 2], a2);                       \
      a3 = fmaf(SC(4 * q + 3), wout[4 * q + 3], a3);                       \
    }                                                                      \
    red[buf][rr][s][o] = (a0 + a1) + (a2 + a3);                            \
  } while (0)

__global__ __launch_bounds__(512)
void snn_coutC(const float* __restrict__ spk, const float* __restrict__ W_out,
               const float* __restrict__ b_out, float* __restrict__ cout,
               int ntc) {
  const int j = threadIdx.x;
  const int o = j & 63;
  const int s = j >> 6;
  const int s_u = __builtin_amdgcn_readfirstlane(s);  // SGPR-addressable
  const size_t row0 = (size_t)blockIdx.x * 64;

  __shared__ float red[2][8][8][64];  // [buf][rowInBatch][slice][o]

  float wout[64];
  {
    const float4* wov =
        reinterpret_cast<const float4*>(W_out) + o * (kH / 4) + s * 16;
#pragma unroll
    for (int q = 0; q < 16; ++q) {
      const float4 v = wov[q];
      wout[4*q+0] = v.x; wout[4*q+1] = v.y;
      wout[4*q+2] = v.z; wout[4*q+3] = v.w;
    }
  }
  float bout = b_out[o];
  PIN8(wout + 0);  PIN8(wout + 8);  PIN8(wout + 16); PIN8(wout + 24);
  PIN8(wout + 32); PIN8(wout + 40); PIN8(wout + 48); PIN8(wout + 56);
  asm volatile("" : "+v"(bout));

#pragma unroll 1
  for (int rb = 0; rb < 64; rb += 8) {
    const int buf = (rb >> 3) & 1;
    const float* spkrow = spk + (row0 + (size_t)rb) * kH + s_u * 64;

    CROW(0); CROW(1); CROW(2); CROW(3);
    CROW(4); CROW(5); CROW(6); CROW(7);

    BARRIER();  // red visible; single barrier per batch (dbuf separation)

    // wave s reduces row rb+s and stores (coalesced 256B)
    float co = bout;
    co += red[buf][s][0][o]; co += red[buf][s][1][o];
    co += red[buf][s][2][o]; co += red[buf][s][3][o];
    co += red[buf][s][4][o]; co += red[buf][s][5][o];
    co += red[buf][s][6][o]; co += red[buf][s][7][o];
    cout[(row0 + (size_t)(rb + s)) * kO + o] = co;
  }
}

// ======================= D: layer-2 scan (per b,o) ========================
#define DSTEP(gk, tt)                                                      \
  do {                                                                     \
    memo = kBeta * memo + (gk) - rsto;                                     \
    const float so = (memo > kThresh) ? 1.0f : 0.0f;                       \
    rsto = so;                                                             \
    om[(size_t)(tt) * kO] = memo;                                          \
    os[(size_t)(tt) * kO] = so;                                            \
    const int tn_ = ((tt) + 8 < ntc) ? (tt) + 8 : ntc - 1;                 \
    gk = dp[(size_t)tn_ * kO];                                             \
  } while (0)

__global__ __launch_bounds__(64)
void snn_memoD(const float* __restrict__ cout, float* __restrict__ out,
               float* __restrict__ state, int t0, int ntc) {
  const int b = blockIdx.x;
  const int o = threadIdx.x;
  float* mos = state + 2 * kB * kH;
  float* ros = mos + kB * kO;
  const int idx = b * kO + o;
  float memo = 0.0f, rsto = 0.0f;
  if (t0 != 0) { memo = mos[idx]; rsto = ros[idx]; }

  const float* dp = cout + (size_t)b * ntc * kO + o;
  float* om = out + ((size_t)b * kT + t0) * kO + o;
  float* os = om + (size_t)kB * kT * kO;

  float g0 = dp[0 * (size_t)kO], g1 = dp[1 * (size_t)kO];
  float g2 = dp[2 * (size_t)kO], g3 = dp[3 * (size_t)kO];
  float g4 = dp[4 * (size_t)kO], g5 = dp[5 * (size_t)kO];
  float g6 = dp[6 * (size_t)kO], g7 = dp[7 * (size_t)kO];

#pragma unroll 1
  for (int t = 0; t < ntc; t += 8) {
    DSTEP(g0, t + 0); DSTEP(g1, t + 1); DSTEP(g2, t + 2); DSTEP(g3, t + 3);
    DSTEP(g4, t + 4); DSTEP(g5, t + 5); DSTEP(g6, t + 6); DSTEP(g7, t + 7);
  }
  mos[idx] = memo;
  ros[idx] = rsto;
}

// ======================= fallback (round-5, proven 1101us) ================
__global__ __launch_bounds__(256)
void warm_x_kernel(const float4* __restrict__ p, int n4) {
  float acc = 0.0f;
  for (int i = blockIdx.x * blockDim.x + threadIdx.x; i < n4;
       i += gridDim.x * blockDim.x) {
    const float4 v = p[i];
    acc += v.x + v.y + v.z + v.w;
  }
  asm volatile("" ::"v"(acc));
}

__global__ __launch_bounds__(512)
__attribute__((amdgpu_waves_per_eu(2, 2)))
void snn_fused5(const float* __restrict__ x, const float* __restrict__ W_in,
                const float* __restrict__ b_in,
                const float* __restrict__ W_out,
                const float* __restrict__ b_out, float* __restrict__ out) {
  const int b = blockIdx.x;
  const int j = threadIdx.x;
  const int o = j & 63;
  const int s = j >> 6;
  __shared__ float red[2][8][64];
  float win[kF];
  {
    const float4* wiv = reinterpret_cast<const float4*>(W_in) + j * 16;
#pragma unroll
    for (int q = 0; q < 16; ++q) {
      const float4 v = wiv[q];
      win[4 * q] = v.x; win[4 * q + 1] = v.y;
      win[4 * q + 2] = v.z; win[4 * q + 3] = v.w;
    }
  }
  float wout[64];
  {
    const float4* wov =
        reinterpret_cast<const float4*>(W_out) + o * 128 + s * 16;
#pragma unroll
    for (int q = 0; q < 16; ++q) {
      const float4 v = wov[q];
      wout[4 * q] = v.x; wout[4 * q + 1] = v.y;
      wout[4 * q + 2] = v.z; wout[4 * q + 3] = v.w;
    }
  }
  float bin_j = b_in[j];
  float bout_o = b_out[o];
  PIN8(win + 0);  PIN8(win + 8);  PIN8(win + 16); PIN8(win + 24);
  PIN8(win + 32); PIN8(win + 40); PIN8(win + 48); PIN8(win + 56);
  PIN8(wout + 0);  PIN8(wout + 8);  PIN8(wout + 16); PIN8(wout + 24);
  PIN8(wout + 32); PIN8(wout + 40); PIN8(wout + 48); PIN8(wout + 56);
  asm volatile("" : "+v"(bin_j), "+v"(bout_o));
  float mem1 = 0.0f, rst1 = 0.0f, memo = 0.0f, rsto = 0.0f;
  unsigned long long mask = 0ull;
  const float4* xv = reinterpret_cast<const float4*>(x + (size_t)b * kT * kF);
  float* out_mem = out + (size_t)b * kT * kO + o;
  float* out_spk = out_mem + (size_t)kB * kT * kO;
  float4 x0, x1, x2, x3, x4, x5, x6, x7, x8, x9, x10, x11, x12, x13, x14, x15;
#define LOADX(tt)                                                          \
  do {                                                                     \
    const float4* xp = xv + (size_t)(tt) * 16;                             \
    x0 = xp[0]; x1 = xp[1]; x2 = xp[2]; x3 = xp[3];                        \
    x4 = xp[4]; x5 = xp[5]; x6 = xp[6]; x7 = xp[7];                        \
    x8 = xp[8]; x9 = xp[9]; x10 = xp[10]; x11 = xp[11];                    \
    x12 = xp[12]; x13 = xp[13]; x14 = xp[14]; x15 = xp[15];                \
  } while (0)
#define L1Q(q)                                                             \
  c0 = fmaf(x##q.x, win[4 * q + 0], c0);                                   \
  c1 = fmaf(x##q.y, win[4 * q + 1], c1);                                   \
  c2 = fmaf(x##q.z, win[4 * q + 2], c2);                                   \
  c3 = fmaf(x##q.w, win[4 * q + 3], c3);
#define LAYER1F()                                                          \
  do {                                                                     \
    float c0 = bin_j, c1 = 0.0f, c2 = 0.0f, c3 = 0.0f;                     \
    L1Q(0) L1Q(1) L1Q(2) L1Q(3) L1Q(4) L1Q(5) L1Q(6) L1Q(7)                \
    L1Q(8) L1Q(9) L1Q(10) L1Q(11) L1Q(12) L1Q(13) L1Q(14) L1Q(15)          \
    const float cur1v = (c0 + c1) + (c2 + c3);                             \
    mem1 = kBeta * mem1 + cur1v - rst1;                                    \
    const bool p = mem1 > kThresh;                                         \
    mask = __ballot(p);                                                    \
    rst1 = p ? 1.0f : 0.0f;                                                \
  } while (0)
#define L2QS(q)                                                            \
  {                                                                        \
    const float f0 = ((mlo >> (4 * (q) + 0)) & 1u) ? 1.0f : 0.0f;          \
    const float f1 = ((mlo >> (4 * (q) + 1)) & 1u) ? 1.0f : 0.0f;          \
    const float f2 = ((mlo >> (4 * (q) + 2)) & 1u) ? 1.0f : 0.0f;          \
    const float f3 = ((mlo >> (4 * (q) + 3)) & 1u) ? 1.0f : 0.0f;          \
    a0 = fmaf(f0, wout[4 * (q) + 0], a0);                                  \
    a1 = fmaf(f1, wout[4 * (q) + 1], a1);                                  \
    a2 = fmaf(f2, wout[4 * (q) + 2], a2);                                  \
    a3 = fmaf(f3, wout[4 * (q) + 3], a3);                                  \
  }
#define L2E(acc, q, i)                                                     \
  acc = acc + __uint_as_float(                                             \
      (unsigned)__builtin_amdgcn_sbfe((int)vmhi, 4 * (q) + (i)-32, 1) &    \
      __float_as_uint(wout[4 * (q) + (i)]));
#define L2QV(q)                                                            \
  { L2E(a0, q, 0) L2E(a1, q, 1) L2E(a2, q, 2) L2E(a3, q, 3) }
#define LAYER2F(buf)                                                       \
  do {                                                                     \
    const unsigned mlo = (unsigned)mask;                                   \
    unsigned vmhi = (unsigned)(mask >> 32);                                \
    asm volatile("" : "+v"(vmhi));                                         \
    float a0 = 0.0f, a1 = 0.0f, a2 = 0.0f, a3 = 0.0f;                      \
    L2QS(0) L2QS(1) L2QS(2) L2QS(3) L2QS(4) L2QS(5) L2QS(6) L2QS(7)        \
    L2QV(8) L2QV(9) L2QV(10) L2QV(11) L2QV(12) L2QV(13) L2QV(14) L2QV(15)  \
    red[(buf)][s][o] = (a0 + a1) + (a2 + a3);                              \
  } while (0)
  LOADX(0);
  LAYER1F();
  LOADX(1);
  for (int t = 1; t < kT; ++t) {
    LAYER2F((t - 1) & 1);
    BARRIER();
    float r0, r1, r2, r3, r4, r5, r6, r7;
    const int buf = (t - 1) & 1;
    if (s == 0) {
      r0 = red[buf][0][o]; r1 = red[buf][1][o];
      r2 = red[buf][2][o]; r3 = red[buf][3][o];
      r4 = red[buf][4][o]; r5 = red[buf][5][o];
      r6 = red[buf][6][o]; r7 = red[buf][7][o];
    }
    LAYER1F();
    const int tn = (t + 1 < kT) ? (t + 1) : (kT - 1);
    LOADX(tn);
    if (s == 0) {
      float co = bout_o;
      co += r0; co += r1; co += r2; co += r3;
      co += r4; co += r5; co += r6; co += r7;
      memo = kBeta * memo + co - rsto;
      const float so = (memo > kThresh) ? 1.0f : 0.0f;
      rsto = so;
      out_mem[(t - 1) * kO] = memo;
      out_spk[(t - 1) * kO] = so;
    }
  }
  LAYER2F((kT - 1) & 1);
  BARRIER();
  if (s == 0) {
    const int buf = (kT - 1) & 1;
    float co = bout_o;
    co += red[buf][0][o]; co += red[buf][1][o];
    co += red[buf][2][o]; co += red[buf][3][o];
    co += red[buf][4][o]; co += red[buf][5][o];
    co += red[buf][6][o]; co += red[buf][7][o];
    memo = kBeta * memo + co - rsto;
    const float so = (memo > kThresh) ? 1.0f : 0.0f;
    out_mem[(kT - 1) * kO] = memo;
    out_spk[(kT - 1) * kO] = so;
  }
}

// ======================= host ==============================================
extern "C" void kernel_launch(void* const* d_in, const int* in_sizes, int n_in,
                              void* d_out, int out_size, void* d_ws,
                              size_t ws_size, hipStream_t stream) {
  const float* x = (const float*)d_in[0];
  const float* W_in = (const float*)d_in[1];
  const float* b_in = (const float*)d_in[2];
  const float* W_out = (const float*)d_in[3];
  const float* b_out = (const float*)d_in[4];
  float* out = (float*)d_out;

  const size_t state_bytes = ((size_t)2 * kB * kH + 2 * kB * kO) * 4;
  int nch = 0;
  for (int c : {4, 8, 16}) {   // nch=2 would spill cur1 past the 256MB L3
    const int ntc_c = kT / c;
    const size_t need = (size_t)kB * ntc_c * (kH + kO) * 4 + state_bytes;
    if (need <= ws_size) { nch = c; break; }
  }

  if (nch) {
    const int ntc = kT / nch;
    const int l2ntc = (ntc == 256) ? 8 : (ntc == 128) ? 7 : 6;
    float* cur1 = (float*)d_ws;                       // also spike buffer
    float* coutb = cur1 + (size_t)kB * ntc * kH;
    float* state = coutb + (size_t)kB * ntc * kO;

    const int rows = kB * ntc;
    const int rpbA = 64;
    const int gA = rows / rpbA;
    const int gC = rows / 64;

    for (int c = 0; c < nch; ++c) {
      const int t0 = c * ntc;
      hipLaunchKernelGGL(snn_curA, dim3(gA), dim3(512), 0, stream,
                         x, W_in, b_in, cur1, t0, ntc, l2ntc, rpbA);
      hipLaunchKernelGGL(snn_scanB, dim3(kB), dim3(512), 0, stream,
                         cur1, state, t0, ntc);
      hipLaunchKernelGGL(snn_coutC, dim3(gC), dim3(512), 0, stream,
                         cur1, W_out, b_out, coutb, ntc);
      hipLaunchKernelGGL(snn_memoD, dim3(kB), dim3(64), 0, stream,
                         coutb, out, state, t0, ntc);
    }
  } else {
    const int n4 = kB * kT * kF / 4;
    hipLaunchKernelGGL(warm_x_kernel, dim3(1024), dim3(256), 0, stream,
                       (const float4*)x, n4);
    hipLaunchKernelGGL(snn_fused5, dim3(kB), dim3(512), 0, stream,
                       x, W_in, b_in, W_out, b_out, out);
  }
}